// Round 2
// baseline (594.535 us; speedup 1.0000x reference)
//
#include <hip/hip_runtime.h>
#include <math.h>

static constexpr int Bn = 64;
static constexpr int Nn = 64;
static constexpr int Mn = 10;
static constexpr int Dn = 512;
static constexpr int NMn = Nn * Mn;      // 640
static constexpr float EPSV = 1e-12f;

typedef unsigned short u16;
typedef __attribute__((ext_vector_type(8))) __bf16 bf16x8;
typedef __attribute__((ext_vector_type(4))) float f32x4;

static __device__ __forceinline__ u16 f2bf(float f) {
  unsigned u = __float_as_uint(f);
  u = u + 0x7fffu + ((u >> 16) & 1u);   // round-to-nearest-even
  return (u16)(u >> 16);
}
static __device__ __forceinline__ float bf2f(u16 h) {
  return __uint_as_float(((unsigned)h) << 16);
}

// ---------------- fast path ----------------
// prep_k: one block per (b,n). Computes normalized centroid -> c hi/lo bf16,
// converts x rows to hi/lo bf16, and per-row squared norms.
__global__ __launch_bounds__(256) void prep_k(const float* __restrict__ x,
                                              u16* __restrict__ xh, u16* __restrict__ xl,
                                              u16* __restrict__ ch, u16* __restrict__ cl,
                                              float* __restrict__ xn2) {
  const int bn = blockIdx.x;  // b*Nn + n
  const int tid = threadIdx.x;
  const float* xp = x + (size_t)bn * (Mn * Dn);
  float v0[Mn], v1[Mn];
  float a0 = 0.f, a1 = 0.f;
#pragma unroll
  for (int m = 0; m < Mn; ++m) {
    v0[m] = xp[m * Dn + tid];
    v1[m] = xp[m * Dn + tid + 256];
    a0 += v0[m]; a1 += v1[m];
  }
  // x -> bf16 hi/lo
  u16* xhp = xh + (size_t)bn * (Mn * Dn);
  u16* xlp = xl + (size_t)bn * (Mn * Dn);
#pragma unroll
  for (int m = 0; m < Mn; ++m) {
    const u16 h0 = f2bf(v0[m]); const u16 l0 = f2bf(v0[m] - bf2f(h0));
    const u16 h1 = f2bf(v1[m]); const u16 l1 = f2bf(v1[m] - bf2f(h1));
    xhp[m * Dn + tid] = h0;        xlp[m * Dn + tid] = l0;
    xhp[m * Dn + tid + 256] = h1;  xlp[m * Dn + tid + 256] = l1;
  }
  // per-row squared norms
  const int wv = tid >> 6, ln = tid & 63;
  __shared__ float part[Mn][4];
#pragma unroll
  for (int m = 0; m < Mn; ++m) {
    float s = v0[m] * v0[m] + v1[m] * v1[m];
#pragma unroll
    for (int t = 1; t < 64; t <<= 1) s += __shfl_xor(s, t, 64);
    if (ln == 0) part[m][wv] = s;
  }
  // centroid norm
  float cs = a0 * a0 + a1 * a1;
#pragma unroll
  for (int t = 1; t < 64; t <<= 1) cs += __shfl_xor(cs, t, 64);
  __shared__ float red[4];
  if (ln == 0) red[wv] = cs;
  __syncthreads();
  if (tid < Mn)
    xn2[(size_t)bn * Mn + tid] = part[tid][0] + part[tid][1] + part[tid][2] + part[tid][3];
  const float tot = red[0] + red[1] + red[2] + red[3];
  const float scale = 1.0f / fmaxf(sqrtf(tot), EPSV);
  const float c0 = a0 * scale, c1 = a1 * scale;
  u16* chp = ch + (size_t)bn * Dn;
  u16* clp = cl + (size_t)bn * Dn;
  const u16 hc0 = f2bf(c0); chp[tid] = hc0;        clp[tid] = f2bf(c0 - bf2f(hc0));
  const u16 hc1 = f2bf(c1); chp[tid + 256] = hc1;  clp[tid + 256] = f2bf(c1 - bf2f(hc1));
}

// gemm_loss_k: one block = 64 rows x 64 centroids of one batch.
// 4 waves, each computes a 16x64 tile via mfma_f32_16x16x32_bf16 with
// hi/lo split (3 MFMA per frag pair), then fused leave-one-out + CE.
__global__ __launch_bounds__(256) void gemm_loss_k(const u16* __restrict__ xh,
                                                   const u16* __restrict__ xl,
                                                   const u16* __restrict__ ch,
                                                   const u16* __restrict__ cl,
                                                   const float* __restrict__ xn2,
                                                   const float* __restrict__ wp,
                                                   const float* __restrict__ bp,
                                                   float* __restrict__ out) {
  const int b = blockIdx.x / (NMn / 64);
  const int rb = blockIdx.x % (NMn / 64);
  const int row0 = rb * 64;
  const int tid = threadIdx.x, wv = tid >> 6, ln = tid & 63;
  const int lr = ln & 15;          // A-row / B-col / D-col fragment index
  const int lkb = (ln >> 4) * 8;   // k offset within 32-wide K-step

  const size_t abase = ((size_t)b * NMn + row0 + wv * 16 + lr) * Dn + lkb;
  const size_t bbase = ((size_t)b * Nn + lr) * Dn + lkb;

  f32x4 acc0 = {0.f, 0.f, 0.f, 0.f};
  f32x4 acc1 = acc0, acc2 = acc0, acc3 = acc0;

#pragma unroll 2
  for (int kk = 0; kk < Dn; kk += 32) {
    const bf16x8 ahi = *(const bf16x8*)(xh + abase + kk);
    const bf16x8 alo = *(const bf16x8*)(xl + abase + kk);
    const bf16x8 bh0 = *(const bf16x8*)(ch + bbase + kk);
    const bf16x8 bh1 = *(const bf16x8*)(ch + bbase + 16 * Dn + kk);
    const bf16x8 bh2 = *(const bf16x8*)(ch + bbase + 32 * Dn + kk);
    const bf16x8 bh3 = *(const bf16x8*)(ch + bbase + 48 * Dn + kk);
    const bf16x8 bl0 = *(const bf16x8*)(cl + bbase + kk);
    const bf16x8 bl1 = *(const bf16x8*)(cl + bbase + 16 * Dn + kk);
    const bf16x8 bl2 = *(const bf16x8*)(cl + bbase + 32 * Dn + kk);
    const bf16x8 bl3 = *(const bf16x8*)(cl + bbase + 48 * Dn + kk);
    acc0 = __builtin_amdgcn_mfma_f32_16x16x32_bf16(ahi, bh0, acc0, 0, 0, 0);
    acc1 = __builtin_amdgcn_mfma_f32_16x16x32_bf16(ahi, bh1, acc1, 0, 0, 0);
    acc2 = __builtin_amdgcn_mfma_f32_16x16x32_bf16(ahi, bh2, acc2, 0, 0, 0);
    acc3 = __builtin_amdgcn_mfma_f32_16x16x32_bf16(ahi, bh3, acc3, 0, 0, 0);
    acc0 = __builtin_amdgcn_mfma_f32_16x16x32_bf16(alo, bh0, acc0, 0, 0, 0);
    acc1 = __builtin_amdgcn_mfma_f32_16x16x32_bf16(alo, bh1, acc1, 0, 0, 0);
    acc2 = __builtin_amdgcn_mfma_f32_16x16x32_bf16(alo, bh2, acc2, 0, 0, 0);
    acc3 = __builtin_amdgcn_mfma_f32_16x16x32_bf16(alo, bh3, acc3, 0, 0, 0);
    acc0 = __builtin_amdgcn_mfma_f32_16x16x32_bf16(ahi, bl0, acc0, 0, 0, 0);
    acc1 = __builtin_amdgcn_mfma_f32_16x16x32_bf16(ahi, bl1, acc1, 0, 0, 0);
    acc2 = __builtin_amdgcn_mfma_f32_16x16x32_bf16(ahi, bl2, acc2, 0, 0, 0);
    acc3 = __builtin_amdgcn_mfma_f32_16x16x32_bf16(ahi, bl3, acc3, 0, 0, 0);
  }

  // C/D layout (verified m89/m91): col = lane&15, row = (lane>>4)*4 + reg
  __shared__ float S[64][65];
  {
    const int orow = wv * 16 + (ln >> 4) * 4;
#pragma unroll
    for (int r = 0; r < 4; ++r) {
      S[orow + r][lr] = acc0[r];
      S[orow + r][16 + lr] = acc1[r];
      S[orow + r][32 + lr] = acc2[r];
      S[orow + r][48 + lr] = acc3[r];
    }
  }
  __syncthreads();

  const float W = *wp, Bb = *bp;
  for (int r = wv; r < 64; r += 4) {
    const int krow = row0 + r;
    const int spk = krow / Mn;
    const float rn = S[r][ln];
    const float x2 = xn2[(size_t)b * NMn + krow];
    const float xn = sqrtf(x2);
    const float inv_xn = 1.0f / fmaxf(xn, EPSV);
    const float rspk = S[r][spk];
    float sv = rn * inv_xn;
    if (ln == spk) {
      const float num = (float)Mn * rspk - x2;
      const float en = sqrtf(fmaxf((float)(Mn * Mn) - 2.0f * (float)Mn * rspk + x2, 0.f));
      sv = num / fmaxf(xn * en, EPSV);
    }
    const float logit = W * sv + Bb;
    const float lspk = __shfl(logit, spk, 64);
    float mx = logit;
#pragma unroll
    for (int t = 1; t < 64; t <<= 1) mx = fmaxf(mx, __shfl_xor(mx, t, 64));
    float se = expf(logit - mx);
#pragma unroll
    for (int t = 1; t < 64; t <<= 1) se += __shfl_xor(se, t, 64);
    const float nll = (mx + logf(se)) - lspk;
    if (ln == 0) atomicAdd(out, nll * (1.0f / (float)(Bn * NMn)));
  }
}

// ---------------- fallback path (round-1, known-good) ----------------
static constexpr int ROWS = 8;
static constexpr int DCHUNK = 128;
static constexpr int CPAD = DCHUNK + 1;

__global__ __launch_bounds__(256) void centroid_k(const float* __restrict__ x,
                                                  float* __restrict__ c) {
  const int bn = blockIdx.x;
  const float* xp = x + (size_t)bn * Mn * Dn;
  const int tid = threadIdx.x;
  float a0 = 0.f, a1 = 0.f;
#pragma unroll
  for (int m = 0; m < Mn; ++m) {
    a0 += xp[m * Dn + tid];
    a1 += xp[m * Dn + tid + 256];
  }
  float s = a0 * a0 + a1 * a1;
#pragma unroll
  for (int m = 1; m < 64; m <<= 1) s += __shfl_xor(s, m, 64);
  __shared__ float red[4];
  const int wv = tid >> 6, ln = tid & 63;
  if (ln == 0) red[wv] = s;
  __syncthreads();
  const float tot = red[0] + red[1] + red[2] + red[3];
  const float scale = 1.0f / fmaxf(sqrtf(tot), EPSV);
  float* cp = c + (size_t)bn * Dn;
  cp[tid] = a0 * scale;
  cp[tid + 256] = a1 * scale;
}

__global__ __launch_bounds__(256) void loss_k(const float* __restrict__ x,
                                              const float* __restrict__ c,
                                              const float* __restrict__ wp,
                                              const float* __restrict__ bp,
                                              float* __restrict__ out) {
  __shared__ __align__(16) float x_lds[ROWS * Dn];
  __shared__ float c_lds[Nn * CPAD];
  __shared__ float xn2s[ROWS];
  __shared__ float sim_lds[ROWS][Nn];

  const int tid = threadIdx.x;
  const int b = blockIdx.x / (NMn / ROWS);
  const int rblk = blockIdx.x % (NMn / ROWS);
  const int row0 = rblk * ROWS;
  const float* xrow = x + ((size_t)b * NMn + row0) * Dn;
  {
    const float4* xs = (const float4*)xrow;
    float4* xd = (float4*)x_lds;
#pragma unroll
    for (int i = tid; i < ROWS * Dn / 4; i += 256) xd[i] = xs[i];
  }
  __syncthreads();
  const int wv = tid >> 6, ln = tid & 63;
  for (int r = wv; r < ROWS; r += 4) {
    float s = 0.f;
#pragma unroll
    for (int j = ln; j < Dn; j += 64) {
      const float v = x_lds[r * Dn + j];
      s += v * v;
    }
#pragma unroll
    for (int m = 1; m < 64; m <<= 1) s += __shfl_xor(s, m, 64);
    if (ln == 0) xn2s[r] = s;
  }
  const int n = tid & 63;
  const int rg = tid >> 6;
  const int r0 = rg * 2, r1 = rg * 2 + 1;
  float s0 = 0.f, s1 = 0.f;
  const float* cb_base = c + (size_t)b * Nn * Dn;
  for (int cb = 0; cb < Dn; cb += DCHUNK) {
    __syncthreads();
    for (int i = tid; i < Nn * DCHUNK; i += 256) {
      const int nn = i / DCHUNK;
      const int j = i & (DCHUNK - 1);
      c_lds[nn * CPAD + j] = cb_base[(size_t)nn * Dn + cb + j];
    }
    __syncthreads();
#pragma unroll 16
    for (int j = 0; j < DCHUNK; ++j) {
      const float cv = c_lds[n * CPAD + j];
      s0 = fmaf(x_lds[r0 * Dn + cb + j], cv, s0);
      s1 = fmaf(x_lds[r1 * Dn + cb + j], cv, s1);
    }
  }
  sim_lds[r0][n] = s0;
  sim_lds[r1][n] = s1;
  __syncthreads();
  const float W = *wp, Bb = *bp;
  for (int r = wv; r < ROWS; r += 4) {
    const int k = row0 + r;
    const int spk = k / Mn;
    const float rn = sim_lds[r][ln];
    const float x2 = xn2s[r];
    const float xn = sqrtf(x2);
    const float inv_xn = 1.0f / fmaxf(xn, EPSV);
    const float rspk = sim_lds[r][spk];
    float sv = rn * inv_xn;
    if (ln == spk) {
      const float num = (float)Mn * rspk - x2;
      const float en = sqrtf(fmaxf((float)(Mn * Mn) - 2.0f * (float)Mn * rspk + x2, 0.f));
      sv = num / fmaxf(xn * en, EPSV);
    }
    const float logit = W * sv + Bb;
    const float lspk = __shfl(logit, spk, 64);
    float mx = logit;
#pragma unroll
    for (int m = 1; m < 64; m <<= 1) mx = fmaxf(mx, __shfl_xor(mx, m, 64));
    float se = expf(logit - mx);
#pragma unroll
    for (int m = 1; m < 64; m <<= 1) se += __shfl_xor(se, m, 64);
    const float nll = (mx + logf(se)) - lspk;
    if (ln == 0) atomicAdd(out, nll * (1.0f / (float)(Bn * NMn)));
  }
}

extern "C" void kernel_launch(void* const* d_in, const int* in_sizes, int n_in,
                              void* d_out, int out_size, void* d_ws, size_t ws_size,
                              hipStream_t stream) {
  const float* x = (const float*)d_in[0];
  const float* w = (const float*)d_in[1];
  const float* b = (const float*)d_in[2];
  float* out = (float*)d_out;

  const size_t XSZ = (size_t)Bn * NMn * Dn * sizeof(u16);   // 41,943,040
  const size_t CSZ = (size_t)Bn * Nn * Dn * sizeof(u16);    //  4,194,304
  const size_t NSZ = (size_t)Bn * NMn * sizeof(float);      //    163,840
  const size_t NEED = 2 * XSZ + 2 * CSZ + NSZ;              // ~88.2 MB

  hipMemsetAsync(out, 0, sizeof(float), stream);

  if (ws_size >= NEED) {
    char* p = (char*)d_ws;
    u16* xh = (u16*)p;            p += XSZ;
    u16* xl = (u16*)p;            p += XSZ;
    u16* ch = (u16*)p;            p += CSZ;
    u16* cl = (u16*)p;            p += CSZ;
    float* xn2 = (float*)p;
    hipLaunchKernelGGL(prep_k, dim3(Bn * Nn), dim3(256), 0, stream,
                       x, xh, xl, ch, cl, xn2);
    hipLaunchKernelGGL(gemm_loss_k, dim3(Bn * (NMn / 64)), dim3(256), 0, stream,
                       xh, xl, ch, cl, xn2, w, b, out);
  } else {
    float* c = (float*)d_ws;  // 8 MB
    hipLaunchKernelGGL(centroid_k, dim3(Bn * Nn), dim3(256), 0, stream, x, c);
    hipLaunchKernelGGL(loss_k, dim3(Bn * (NMn / ROWS)), dim3(256), 0, stream,
                       x, c, w, b, out);
  }
}

// Round 3
// 94.883 us; speedup vs baseline: 6.2660x; 6.2660x over previous
//
#include <hip/hip_runtime.h>
#include <math.h>

static constexpr int Bn = 64;
static constexpr int Nn = 64;
static constexpr int Mn = 10;
static constexpr int Dn = 512;
static constexpr int NMn = Nn * Mn;      // 640
static constexpr float EPSV = 1e-12f;

typedef unsigned short u16;
typedef __attribute__((ext_vector_type(8))) __bf16 bf16x8;
typedef __attribute__((ext_vector_type(8))) u16 u16x8;
typedef __attribute__((ext_vector_type(4))) float f32x4;

static __device__ __forceinline__ u16 f2bf(float f) {
  unsigned u = __float_as_uint(f);
  u = u + 0x7fffu + ((u >> 16) & 1u);   // round-to-nearest-even
  return (u16)(u >> 16);
}
static __device__ __forceinline__ float bf2f(u16 h) {
  return __uint_as_float(((unsigned)h) << 16);
}

// ---------------- fast path ----------------
// Kernel 1: per (b,n): normalized centroid -> bf16 hi/lo, per-row sq norms.
__global__ __launch_bounds__(256) void centroid_k(const float* __restrict__ x,
                                                  u16* __restrict__ ch, u16* __restrict__ cl,
                                                  float* __restrict__ xn2) {
  const int bn = blockIdx.x;  // b*Nn + n
  const int tid = threadIdx.x;
  const float* xp = x + (size_t)bn * (Mn * Dn);
  float v0[Mn], v1[Mn];
  float a0 = 0.f, a1 = 0.f;
#pragma unroll
  for (int m = 0; m < Mn; ++m) {
    v0[m] = xp[m * Dn + tid];
    v1[m] = xp[m * Dn + tid + 256];
    a0 += v0[m]; a1 += v1[m];
  }
  const int wv = tid >> 6, ln = tid & 63;
  __shared__ float part[Mn][4];
#pragma unroll
  for (int m = 0; m < Mn; ++m) {
    float s = v0[m] * v0[m] + v1[m] * v1[m];
#pragma unroll
    for (int t = 1; t < 64; t <<= 1) s += __shfl_xor(s, t, 64);
    if (ln == 0) part[m][wv] = s;
  }
  float cs = a0 * a0 + a1 * a1;
#pragma unroll
  for (int t = 1; t < 64; t <<= 1) cs += __shfl_xor(cs, t, 64);
  __shared__ float red[4];
  if (ln == 0) red[wv] = cs;
  __syncthreads();
  if (tid < Mn)
    xn2[(size_t)bn * Mn + tid] = part[tid][0] + part[tid][1] + part[tid][2] + part[tid][3];
  const float tot = red[0] + red[1] + red[2] + red[3];
  const float scale = 1.0f / fmaxf(sqrtf(tot), EPSV);
  const float c0 = a0 * scale, c1 = a1 * scale;
  u16* chp = ch + (size_t)bn * Dn;
  u16* clp = cl + (size_t)bn * Dn;
  const u16 hc0 = f2bf(c0); chp[tid] = hc0;        clp[tid] = f2bf(c0 - bf2f(hc0));
  const u16 hc1 = f2bf(c1); chp[tid + 256] = hc1;  clp[tid + 256] = f2bf(c1 - bf2f(hc1));
}

// Kernel 2: 64 rows x 64 centroids per block; A loaded fp32 from x and split
// to bf16 hi/lo in registers; 3-pass MFMA; fused CE; ONE atomic per block.
__global__ __launch_bounds__(256) void gemm_loss_k(const float* __restrict__ x,
                                                   const u16* __restrict__ ch,
                                                   const u16* __restrict__ cl,
                                                   const float* __restrict__ xn2,
                                                   const float* __restrict__ wp,
                                                   const float* __restrict__ bp,
                                                   float* __restrict__ out) {
  const int b = blockIdx.x / (NMn / 64);
  const int rb = blockIdx.x % (NMn / 64);
  const int row0 = rb * 64;
  const int tid = threadIdx.x, wv = tid >> 6, ln = tid & 63;
  const int lr = ln & 15;          // fragment row/col index
  const int lkb = (ln >> 4) * 8;   // k offset within 32-wide K-step

  const float* arow = x + ((size_t)b * NMn + row0 + wv * 16 + lr) * Dn + lkb;
  const size_t bbase = ((size_t)b * Nn + lr) * Dn + lkb;

  f32x4 acc0 = {0.f, 0.f, 0.f, 0.f};
  f32x4 acc1 = acc0, acc2 = acc0, acc3 = acc0;

#pragma unroll 2
  for (int kk = 0; kk < Dn; kk += 32) {
    const float4 f0 = *(const float4*)(arow + kk);
    const float4 f1 = *(const float4*)(arow + kk + 4);
    const bf16x8 bh0 = *(const bf16x8*)(ch + bbase + kk);
    const bf16x8 bh1 = *(const bf16x8*)(ch + bbase + 16 * Dn + kk);
    const bf16x8 bh2 = *(const bf16x8*)(ch + bbase + 32 * Dn + kk);
    const bf16x8 bh3 = *(const bf16x8*)(ch + bbase + 48 * Dn + kk);
    const bf16x8 bl0 = *(const bf16x8*)(cl + bbase + kk);
    const bf16x8 bl1 = *(const bf16x8*)(cl + bbase + 16 * Dn + kk);
    const bf16x8 bl2 = *(const bf16x8*)(cl + bbase + 32 * Dn + kk);
    const bf16x8 bl3 = *(const bf16x8*)(cl + bbase + 48 * Dn + kk);

    const float v[8] = {f0.x, f0.y, f0.z, f0.w, f1.x, f1.y, f1.z, f1.w};
    u16x8 hh, ll;
#pragma unroll
    for (int i = 0; i < 8; ++i) {
      const u16 h = f2bf(v[i]);
      hh[i] = h;
      ll[i] = f2bf(v[i] - bf2f(h));
    }
    const bf16x8 ahi = __builtin_bit_cast(bf16x8, hh);
    const bf16x8 alo = __builtin_bit_cast(bf16x8, ll);

    acc0 = __builtin_amdgcn_mfma_f32_16x16x32_bf16(ahi, bh0, acc0, 0, 0, 0);
    acc1 = __builtin_amdgcn_mfma_f32_16x16x32_bf16(ahi, bh1, acc1, 0, 0, 0);
    acc2 = __builtin_amdgcn_mfma_f32_16x16x32_bf16(ahi, bh2, acc2, 0, 0, 0);
    acc3 = __builtin_amdgcn_mfma_f32_16x16x32_bf16(ahi, bh3, acc3, 0, 0, 0);
    acc0 = __builtin_amdgcn_mfma_f32_16x16x32_bf16(alo, bh0, acc0, 0, 0, 0);
    acc1 = __builtin_amdgcn_mfma_f32_16x16x32_bf16(alo, bh1, acc1, 0, 0, 0);
    acc2 = __builtin_amdgcn_mfma_f32_16x16x32_bf16(alo, bh2, acc2, 0, 0, 0);
    acc3 = __builtin_amdgcn_mfma_f32_16x16x32_bf16(alo, bh3, acc3, 0, 0, 0);
    acc0 = __builtin_amdgcn_mfma_f32_16x16x32_bf16(ahi, bl0, acc0, 0, 0, 0);
    acc1 = __builtin_amdgcn_mfma_f32_16x16x32_bf16(ahi, bl1, acc1, 0, 0, 0);
    acc2 = __builtin_amdgcn_mfma_f32_16x16x32_bf16(ahi, bl2, acc2, 0, 0, 0);
    acc3 = __builtin_amdgcn_mfma_f32_16x16x32_bf16(ahi, bl3, acc3, 0, 0, 0);
  }

  // C/D layout: col = lane&15, row = (lane>>4)*4 + reg
  __shared__ float S[64][65];
  {
    const int orow = wv * 16 + (ln >> 4) * 4;
#pragma unroll
    for (int r = 0; r < 4; ++r) {
      S[orow + r][lr] = acc0[r];
      S[orow + r][16 + lr] = acc1[r];
      S[orow + r][32 + lr] = acc2[r];
      S[orow + r][48 + lr] = acc3[r];
    }
  }
  __syncthreads();

  const float W = *wp, Bb = *bp;
  float acc_nll = 0.f;
  for (int r = wv; r < 64; r += 4) {
    const int krow = row0 + r;
    const int spk = krow / Mn;
    const float rn = S[r][ln];
    const float x2 = xn2[(size_t)b * NMn + krow];
    const float xn = sqrtf(x2);
    const float inv_xn = 1.0f / fmaxf(xn, EPSV);
    const float rspk = S[r][spk];
    float sv = rn * inv_xn;
    if (ln == spk) {
      const float num = (float)Mn * rspk - x2;
      const float en = sqrtf(fmaxf((float)(Mn * Mn) - 2.0f * (float)Mn * rspk + x2, 0.f));
      sv = num / fmaxf(xn * en, EPSV);
    }
    const float logit = W * sv + Bb;
    const float lspk = __shfl(logit, spk, 64);
    float mx = logit;
#pragma unroll
    for (int t = 1; t < 64; t <<= 1) mx = fmaxf(mx, __shfl_xor(mx, t, 64));
    float se = expf(logit - mx);
#pragma unroll
    for (int t = 1; t < 64; t <<= 1) se += __shfl_xor(se, t, 64);
    acc_nll += (mx + logf(se)) - lspk;   // wave-uniform after reductions
  }
  __shared__ float nred[4];
  if (ln == 0) nred[wv] = acc_nll;
  __syncthreads();
  if (tid == 0)
    atomicAdd(out, (nred[0] + nred[1] + nred[2] + nred[3]) * (1.0f / (float)(Bn * NMn)));
}

// ---------------- fallback path (round-1, known-good) ----------------
static constexpr int ROWS = 8;
static constexpr int DCHUNK = 128;
static constexpr int CPAD = DCHUNK + 1;

__global__ __launch_bounds__(256) void centroid_fb_k(const float* __restrict__ x,
                                                     float* __restrict__ c) {
  const int bn = blockIdx.x;
  const float* xp = x + (size_t)bn * Mn * Dn;
  const int tid = threadIdx.x;
  float a0 = 0.f, a1 = 0.f;
#pragma unroll
  for (int m = 0; m < Mn; ++m) {
    a0 += xp[m * Dn + tid];
    a1 += xp[m * Dn + tid + 256];
  }
  float s = a0 * a0 + a1 * a1;
#pragma unroll
  for (int m = 1; m < 64; m <<= 1) s += __shfl_xor(s, m, 64);
  __shared__ float red[4];
  const int wv = tid >> 6, ln = tid & 63;
  if (ln == 0) red[wv] = s;
  __syncthreads();
  const float tot = red[0] + red[1] + red[2] + red[3];
  const float scale = 1.0f / fmaxf(sqrtf(tot), EPSV);
  float* cp = c + (size_t)bn * Dn;
  cp[tid] = a0 * scale;
  cp[tid + 256] = a1 * scale;
}

__global__ __launch_bounds__(256) void loss_fb_k(const float* __restrict__ x,
                                                 const float* __restrict__ c,
                                                 const float* __restrict__ wp,
                                                 const float* __restrict__ bp,
                                                 float* __restrict__ out) {
  __shared__ __align__(16) float x_lds[ROWS * Dn];
  __shared__ float c_lds[Nn * CPAD];
  __shared__ float xn2s[ROWS];
  __shared__ float sim_lds[ROWS][Nn];

  const int tid = threadIdx.x;
  const int b = blockIdx.x / (NMn / ROWS);
  const int rblk = blockIdx.x % (NMn / ROWS);
  const int row0 = rblk * ROWS;
  const float* xrow = x + ((size_t)b * NMn + row0) * Dn;
  {
    const float4* xs = (const float4*)xrow;
    float4* xd = (float4*)x_lds;
#pragma unroll
    for (int i = tid; i < ROWS * Dn / 4; i += 256) xd[i] = xs[i];
  }
  __syncthreads();
  const int wv = tid >> 6, ln = tid & 63;
  for (int r = wv; r < ROWS; r += 4) {
    float s = 0.f;
#pragma unroll
    for (int j = ln; j < Dn; j += 64) {
      const float v = x_lds[r * Dn + j];
      s += v * v;
    }
#pragma unroll
    for (int m = 1; m < 64; m <<= 1) s += __shfl_xor(s, m, 64);
    if (ln == 0) xn2s[r] = s;
  }
  const int n = tid & 63;
  const int rg = tid >> 6;
  const int r0 = rg * 2, r1 = rg * 2 + 1;
  float s0 = 0.f, s1 = 0.f;
  const float* cb_base = c + (size_t)b * Nn * Dn;
  for (int cb = 0; cb < Dn; cb += DCHUNK) {
    __syncthreads();
    for (int i = tid; i < Nn * DCHUNK; i += 256) {
      const int nn = i / DCHUNK;
      const int j = i & (DCHUNK - 1);
      c_lds[nn * CPAD + j] = cb_base[(size_t)nn * Dn + cb + j];
    }
    __syncthreads();
#pragma unroll 16
    for (int j = 0; j < DCHUNK; ++j) {
      const float cv = c_lds[n * CPAD + j];
      s0 = fmaf(x_lds[r0 * Dn + cb + j], cv, s0);
      s1 = fmaf(x_lds[r1 * Dn + cb + j], cv, s1);
    }
  }
  sim_lds[r0][n] = s0;
  sim_lds[r1][n] = s1;
  __syncthreads();
  const float W = *wp, Bb = *bp;
  float acc_nll = 0.f;
  for (int r = wv; r < ROWS; r += 4) {
    const int k = row0 + r;
    const int spk = k / Mn;
    const float rn = sim_lds[r][ln];
    const float x2 = xn2s[r];
    const float xn = sqrtf(x2);
    const float inv_xn = 1.0f / fmaxf(xn, EPSV);
    const float rspk = sim_lds[r][spk];
    float sv = rn * inv_xn;
    if (ln == spk) {
      const float num = (float)Mn * rspk - x2;
      const float en = sqrtf(fmaxf((float)(Mn * Mn) - 2.0f * (float)Mn * rspk + x2, 0.f));
      sv = num / fmaxf(xn * en, EPSV);
    }
    const float logit = W * sv + Bb;
    const float lspk = __shfl(logit, spk, 64);
    float mx = logit;
#pragma unroll
    for (int m = 1; m < 64; m <<= 1) mx = fmaxf(mx, __shfl_xor(mx, m, 64));
    float se = expf(logit - mx);
#pragma unroll
    for (int m = 1; m < 64; m <<= 1) se += __shfl_xor(se, m, 64);
    acc_nll += (mx + logf(se)) - lspk;
  }
  __shared__ float nred[4];
  if (ln == 0) nred[wv] = acc_nll;
  __syncthreads();
  if (tid == 0)
    atomicAdd(out, (nred[0] + nred[1] + nred[2] + nred[3]) * (1.0f / (float)(Bn * NMn)));
}

extern "C" void kernel_launch(void* const* d_in, const int* in_sizes, int n_in,
                              void* d_out, int out_size, void* d_ws, size_t ws_size,
                              hipStream_t stream) {
  const float* x = (const float*)d_in[0];
  const float* w = (const float*)d_in[1];
  const float* b = (const float*)d_in[2];
  float* out = (float*)d_out;

  const size_t CSZ = (size_t)Bn * Nn * Dn * sizeof(u16);    // 4,194,304
  const size_t NSZ = (size_t)Bn * NMn * sizeof(float);      //   163,840
  const size_t NEED = 2 * CSZ + NSZ;                        // ~8.6 MB

  hipMemsetAsync(out, 0, sizeof(float), stream);

  if (ws_size >= NEED) {
    char* p = (char*)d_ws;
    u16* ch = (u16*)p;   p += CSZ;
    u16* cl = (u16*)p;   p += CSZ;
    float* xn2 = (float*)p;
    hipLaunchKernelGGL(centroid_k, dim3(Bn * Nn), dim3(256), 0, stream,
                       x, ch, cl, xn2);
    hipLaunchKernelGGL(gemm_loss_k, dim3(Bn * (NMn / 64)), dim3(256), 0, stream,
                       x, ch, cl, xn2, w, b, out);
  } else {
    float* c = (float*)d_ws;  // 8 MB
    hipLaunchKernelGGL(centroid_fb_k, dim3(Bn * Nn), dim3(256), 0, stream, x, c);
    hipLaunchKernelGGL(loss_fb_k, dim3(Bn * (NMn / ROWS)), dim3(256), 0, stream,
                       x, c, w, b, out);
  }
}

// Round 4
// 54.941 us; speedup vs baseline: 10.8213x; 1.7270x over previous
//
#include <hip/hip_runtime.h>
#include <math.h>

static constexpr int Bn = 64;
static constexpr int Nn = 64;
static constexpr int Mn = 10;
static constexpr int Dn = 512;
static constexpr int NMn = Nn * Mn;      // 640
static constexpr int RT = 16;            // rows per block (kernel 2)
static constexpr int NBLK2 = Bn * (NMn / RT);  // 2560
static constexpr float EPSV = 1e-12f;

typedef unsigned short u16;
typedef unsigned int u32;
typedef __attribute__((ext_vector_type(8))) __bf16 bf16x8;
typedef __attribute__((ext_vector_type(8))) u16 u16x8;
typedef __attribute__((ext_vector_type(4))) float f32x4;

static __device__ __forceinline__ u16 f2bf(float f) {
  u32 u = __float_as_uint(f);
  u = u + 0x7fffu + ((u >> 16) & 1u);   // round-to-nearest-even
  return (u16)(u >> 16);
}

// ---------------- fast path ----------------
// Kernel 1: per (b,n): normalized centroid (bf16) + per-utterance sq-norms.
// float4 loads: thread t handles float4-col f4=t&127 for the 5 m's of parity mg=t>>7.
__global__ __launch_bounds__(256) void centroid_k(const float* __restrict__ x,
                                                  u16* __restrict__ ch,
                                                  float* __restrict__ xn2) {
  const int bn = blockIdx.x;          // b*Nn + n
  const int tid = threadIdx.x;
  const int f4 = tid & 127;
  const int mg = tid >> 7;            // 0: m even (waves 0,1), 1: m odd (waves 2,3)
  const int wv = tid >> 6, ln = tid & 63;
  const float4* xp = (const float4*)(x + (size_t)bn * (Mn * Dn));

  float4 a = {0.f, 0.f, 0.f, 0.f};
  float sq[5];
#pragma unroll
  for (int k = 0; k < 5; ++k) {
    const float4 v = xp[(2 * k + mg) * 128 + f4];
    a.x += v.x; a.y += v.y; a.z += v.z; a.w += v.w;
    sq[k] = v.x * v.x + v.y * v.y + v.z * v.z + v.w * v.w;
  }
#pragma unroll
  for (int k = 0; k < 5; ++k) {
#pragma unroll
    for (int t = 1; t < 64; t <<= 1) sq[k] += __shfl_xor(sq[k], t, 64);
  }
  __shared__ float sqred[4][5];
  if (ln == 0) {
#pragma unroll
    for (int k = 0; k < 5; ++k) sqred[wv][k] = sq[k];
  }
  __shared__ float4 cred[128];
  if (mg == 1) cred[f4] = a;
  __syncthreads();

  if (tid < Mn) {   // per-utterance squared norms
    const int par = tid & 1, k = tid >> 1;
    xn2[(size_t)bn * Mn + tid] = sqred[2 * par][k] + sqred[2 * par + 1][k];
  }

  float4 c = {0.f, 0.f, 0.f, 0.f};
  float cs = 0.f;
  if (mg == 0) {
    c = cred[f4];
    c.x += a.x; c.y += a.y; c.z += a.z; c.w += a.w;
    cs = c.x * c.x + c.y * c.y + c.z * c.z + c.w * c.w;
  }
#pragma unroll
  for (int t = 1; t < 64; t <<= 1) cs += __shfl_xor(cs, t, 64);
  __shared__ float csred[2];
  if (mg == 0 && ln == 0) csred[wv] = cs;
  __syncthreads();
  if (mg == 0) {
    const float scale = 1.0f / fmaxf(sqrtf(csred[0] + csred[1]), EPSV);
    const u16 h0 = f2bf(c.x * scale), h1 = f2bf(c.y * scale);
    const u16 h2 = f2bf(c.z * scale), h3 = f2bf(c.w * scale);
    uint2 w;
    w.x = (u32)h0 | ((u32)h1 << 16);
    w.y = (u32)h2 | ((u32)h3 << 16);
    ((uint2*)(ch + (size_t)bn * Dn))[f4] = w;
  }
}

// Kernel 2: 16 rows x 64 centroids per block; 4 waves split K (128 each).
// Pure bf16 MFMA (A converted fp32->bf16 in-reg). Fused CE, partial per block.
__global__ __launch_bounds__(256) void gemm_loss_k(const float* __restrict__ x,
                                                   const u16* __restrict__ ch,
                                                   const float* __restrict__ xn2,
                                                   const float* __restrict__ wp,
                                                   const float* __restrict__ bp,
                                                   float* __restrict__ partial) {
  const int b = blockIdx.x / (NMn / RT);
  const int rt = blockIdx.x % (NMn / RT);
  const int row0 = rt * RT;
  const int tid = threadIdx.x, wv = tid >> 6, ln = tid & 63;
  const int lr = ln & 15;          // A-row / B-col fragment index
  const int lkb = (ln >> 4) * 8;   // k offset within 32-wide K-step
  const int k0 = wv * 128;         // this wave's K-quarter

  const float* arow = x + ((size_t)b * NMn + row0 + lr) * Dn + k0 + lkb;
  const u16* brow = ch + ((size_t)b * Nn + lr) * Dn + k0 + lkb;

  f32x4 acc0 = {0.f, 0.f, 0.f, 0.f};
  f32x4 acc1 = acc0, acc2 = acc0, acc3 = acc0;

#pragma unroll
  for (int kk = 0; kk < 128; kk += 32) {
    const float4 f0 = *(const float4*)(arow + kk);
    const float4 f1 = *(const float4*)(arow + kk + 4);
    const bf16x8 b0 = *(const bf16x8*)(brow + kk);
    const bf16x8 b1 = *(const bf16x8*)(brow + 16 * Dn + kk);
    const bf16x8 b2 = *(const bf16x8*)(brow + 32 * Dn + kk);
    const bf16x8 b3 = *(const bf16x8*)(brow + 48 * Dn + kk);
    const float v[8] = {f0.x, f0.y, f0.z, f0.w, f1.x, f1.y, f1.z, f1.w};
    u16x8 hh;
#pragma unroll
    for (int i = 0; i < 8; ++i) hh[i] = f2bf(v[i]);
    const bf16x8 ah = __builtin_bit_cast(bf16x8, hh);
    acc0 = __builtin_amdgcn_mfma_f32_16x16x32_bf16(ah, b0, acc0, 0, 0, 0);
    acc1 = __builtin_amdgcn_mfma_f32_16x16x32_bf16(ah, b1, acc1, 0, 0, 0);
    acc2 = __builtin_amdgcn_mfma_f32_16x16x32_bf16(ah, b2, acc2, 0, 0, 0);
    acc3 = __builtin_amdgcn_mfma_f32_16x16x32_bf16(ah, b3, acc3, 0, 0, 0);
  }

  // C/D layout: col = lane&15, row = (lane>>4)*4 + reg  (verified rounds 2-3)
  __shared__ float S[4][RT][65];   // per-wave partial sums, 16.6 KB
  const int orow = (ln >> 4) * 4;
#pragma unroll
  for (int r = 0; r < 4; ++r) {
    S[wv][orow + r][lr] = acc0[r];
    S[wv][orow + r][16 + lr] = acc1[r];
    S[wv][orow + r][32 + lr] = acc2[r];
    S[wv][orow + r][48 + lr] = acc3[r];
  }
  __syncthreads();

  // CE: wave wv handles rows wv*4 .. wv*4+3; lanes = 64 speaker columns
  const float W = *wp, Bb = *bp;
  float acc_nll = 0.f;
#pragma unroll
  for (int i = 0; i < 4; ++i) {
    const int r = wv * 4 + i;
    const int krow = row0 + r;
    const int spk = krow / Mn;
    const float rn = S[0][r][ln] + S[1][r][ln] + S[2][r][ln] + S[3][r][ln];
    const float x2 = xn2[(size_t)b * NMn + krow];
    const float xn = sqrtf(x2);
    const float inv_xn = 1.0f / fmaxf(xn, EPSV);
    const float rspk = __shfl(rn, spk, 64);
    float sv = rn * inv_xn;
    if (ln == spk) {
      const float num = (float)Mn * rspk - x2;
      const float en = sqrtf(fmaxf((float)(Mn * Mn) - 2.0f * (float)Mn * rspk + x2, 0.f));
      sv = num / fmaxf(xn * en, EPSV);
    }
    const float logit = W * sv + Bb;
    const float lspk = __shfl(logit, spk, 64);
    float mx = logit;
#pragma unroll
    for (int t = 1; t < 64; t <<= 1) mx = fmaxf(mx, __shfl_xor(mx, t, 64));
    float se = expf(logit - mx);
#pragma unroll
    for (int t = 1; t < 64; t <<= 1) se += __shfl_xor(se, t, 64);
    acc_nll += (mx + logf(se)) - lspk;   // wave-uniform
  }
  __shared__ float nred[4];
  if (ln == 0) nred[wv] = acc_nll;
  __syncthreads();
  if (tid == 0) partial[blockIdx.x] = nred[0] + nred[1] + nred[2] + nred[3];
}

// Kernel 3: deterministic final reduction of 2560 per-block partials.
__global__ __launch_bounds__(256) void reduce_k(const float* __restrict__ partial,
                                                float* __restrict__ out) {
  const int tid = threadIdx.x;
  float s = 0.f;
  for (int i = tid; i < NBLK2; i += 256) s += partial[i];
#pragma unroll
  for (int t = 1; t < 64; t <<= 1) s += __shfl_xor(s, t, 64);
  __shared__ float red[4];
  if ((tid & 63) == 0) red[tid >> 6] = s;
  __syncthreads();
  if (tid == 0) out[0] = (red[0] + red[1] + red[2] + red[3]) * (1.0f / (float)(Bn * NMn));
}

// ---------------- fallback path (round-1 structure, known-good) ----------------
static constexpr int ROWS = 8;
static constexpr int DCHUNK = 128;
static constexpr int CPAD = DCHUNK + 1;

__global__ __launch_bounds__(256) void centroid_fb_k(const float* __restrict__ x,
                                                     float* __restrict__ c) {
  const int bn = blockIdx.x;
  const float* xp = x + (size_t)bn * Mn * Dn;
  const int tid = threadIdx.x;
  float a0 = 0.f, a1 = 0.f;
#pragma unroll
  for (int m = 0; m < Mn; ++m) {
    a0 += xp[m * Dn + tid];
    a1 += xp[m * Dn + tid + 256];
  }
  float s = a0 * a0 + a1 * a1;
#pragma unroll
  for (int m = 1; m < 64; m <<= 1) s += __shfl_xor(s, m, 64);
  __shared__ float red[4];
  const int wv = tid >> 6, ln = tid & 63;
  if (ln == 0) red[wv] = s;
  __syncthreads();
  const float tot = red[0] + red[1] + red[2] + red[3];
  const float scale = 1.0f / fmaxf(sqrtf(tot), EPSV);
  float* cp = c + (size_t)bn * Dn;
  cp[tid] = a0 * scale;
  cp[tid + 256] = a1 * scale;
}

__global__ __launch_bounds__(256) void loss_fb_k(const float* __restrict__ x,
                                                 const float* __restrict__ c,
                                                 const float* __restrict__ wp,
                                                 const float* __restrict__ bp,
                                                 float* __restrict__ out) {
  __shared__ __align__(16) float x_lds[ROWS * Dn];
  __shared__ float c_lds[Nn * CPAD];
  __shared__ float xn2s[ROWS];
  __shared__ float sim_lds[ROWS][Nn];

  const int tid = threadIdx.x;
  const int b = blockIdx.x / (NMn / ROWS);
  const int rblk = blockIdx.x % (NMn / ROWS);
  const int row0 = rblk * ROWS;
  const float* xrow = x + ((size_t)b * NMn + row0) * Dn;
  {
    const float4* xs = (const float4*)xrow;
    float4* xd = (float4*)x_lds;
#pragma unroll
    for (int i = tid; i < ROWS * Dn / 4; i += 256) xd[i] = xs[i];
  }
  __syncthreads();
  const int wv = tid >> 6, ln = tid & 63;
  for (int r = wv; r < ROWS; r += 4) {
    float s = 0.f;
#pragma unroll
    for (int j = ln; j < Dn; j += 64) {
      const float v = x_lds[r * Dn + j];
      s += v * v;
    }
#pragma unroll
    for (int m = 1; m < 64; m <<= 1) s += __shfl_xor(s, m, 64);
    if (ln == 0) xn2s[r] = s;
  }
  const int n = tid & 63;
  const int rg = tid >> 6;
  const int r0 = rg * 2, r1 = rg * 2 + 1;
  float s0 = 0.f, s1 = 0.f;
  const float* cb_base = c + (size_t)b * Nn * Dn;
  for (int cb = 0; cb < Dn; cb += DCHUNK) {
    __syncthreads();
    for (int i = tid; i < Nn * DCHUNK; i += 256) {
      const int nn = i / DCHUNK;
      const int j = i & (DCHUNK - 1);
      c_lds[nn * CPAD + j] = cb_base[(size_t)nn * Dn + cb + j];
    }
    __syncthreads();
#pragma unroll 16
    for (int j = 0; j < DCHUNK; ++j) {
      const float cv = c_lds[n * CPAD + j];
      s0 = fmaf(x_lds[r0 * Dn + cb + j], cv, s0);
      s1 = fmaf(x_lds[r1 * Dn + cb + j], cv, s1);
    }
  }
  sim_lds[r0][n] = s0;
  sim_lds[r1][n] = s1;
  __syncthreads();
  const float W = *wp, Bb = *bp;
  float acc_nll = 0.f;
  for (int r = wv; r < ROWS; r += 4) {
    const int k = row0 + r;
    const int spk = k / Mn;
    const float rn = sim_lds[r][ln];
    const float x2 = xn2s[r];
    const float xn = sqrtf(x2);
    const float inv_xn = 1.0f / fmaxf(xn, EPSV);
    const float rspk = sim_lds[r][spk];
    float sv = rn * inv_xn;
    if (ln == spk) {
      const float num = (float)Mn * rspk - x2;
      const float en = sqrtf(fmaxf((float)(Mn * Mn) - 2.0f * (float)Mn * rspk + x2, 0.f));
      sv = num / fmaxf(xn * en, EPSV);
    }
    const float logit = W * sv + Bb;
    const float lspk = __shfl(logit, spk, 64);
    float mx = logit;
#pragma unroll
    for (int m = 1; m < 64; m <<= 1) mx = fmaxf(mx, __shfl_xor(mx, m, 64));
    float se = expf(logit - mx);
#pragma unroll
    for (int m = 1; m < 64; m <<= 1) se += __shfl_xor(se, m, 64);
    acc_nll += (mx + logf(se)) - lspk;
  }
  __shared__ float nred[4];
  if (ln == 0) nred[wv] = acc_nll;
  __syncthreads();
  if (tid == 0)
    atomicAdd(out, (nred[0] + nred[1] + nred[2] + nred[3]) * (1.0f / (float)(Bn * NMn)));
}

extern "C" void kernel_launch(void* const* d_in, const int* in_sizes, int n_in,
                              void* d_out, int out_size, void* d_ws, size_t ws_size,
                              hipStream_t stream) {
  const float* x = (const float*)d_in[0];
  const float* w = (const float*)d_in[1];
  const float* b = (const float*)d_in[2];
  float* out = (float*)d_out;

  const size_t CSZ = (size_t)Bn * Nn * Dn * sizeof(u16);    // 4,194,304
  const size_t NSZ = (size_t)Bn * NMn * sizeof(float);      //   163,840
  const size_t PSZ = (size_t)NBLK2 * sizeof(float);         //    10,240
  const size_t NEED = CSZ + NSZ + PSZ;                      //  ~4.4 MB

  if (ws_size >= NEED) {
    char* p = (char*)d_ws;
    u16* ch = (u16*)p;      p += CSZ;
    float* xn2 = (float*)p; p += NSZ;
    float* partial = (float*)p;
    hipLaunchKernelGGL(centroid_k, dim3(Bn * Nn), dim3(256), 0, stream, x, ch, xn2);
    hipLaunchKernelGGL(gemm_loss_k, dim3(NBLK2), dim3(256), 0, stream,
                       x, ch, xn2, w, b, partial);
    hipLaunchKernelGGL(reduce_k, dim3(1), dim3(256), 0, stream, partial, out);
  } else {
    float* c = (float*)d_ws;  // 8 MB
    hipMemsetAsync(out, 0, sizeof(float), stream);
    hipLaunchKernelGGL(centroid_fb_k, dim3(Bn * Nn), dim3(256), 0, stream, x, c);
    hipLaunchKernelGGL(loss_fb_k, dim3(Bn * (NMn / ROWS)), dim3(256), 0, stream,
                       x, c, w, b, out);
  }
}

// Round 5
// 53.631 us; speedup vs baseline: 11.0856x; 1.0244x over previous
//
#include <hip/hip_runtime.h>
#include <math.h>

static constexpr int Bn = 64;
static constexpr int Nn = 64;
static constexpr int Mn = 10;
static constexpr int Dn = 512;
static constexpr int NMn = Nn * Mn;      // 640
static constexpr int RT = 16;            // rows per block (kernel 2)
static constexpr int NBLK2 = Bn * (NMn / RT);  // 2560
static constexpr float EPSV = 1e-12f;

typedef unsigned short u16;
typedef unsigned int u32;
typedef __attribute__((ext_vector_type(8))) __bf16 bf16x8;
typedef __attribute__((ext_vector_type(4))) float f32x4;

static __device__ __forceinline__ u16 f2bf(float f) {
  u32 u = __float_as_uint(f);
  u = u + 0x7fffu + ((u >> 16) & 1u);   // round-to-nearest-even
  return (u16)(u >> 16);
}

// ---------------- fast path ----------------
// Kernel 1: per (b,n): normalized centroid -> bf16. Lean: no norms here.
// Thread t: float4-column f4=t&127, parity mg=t>>7 covers m = 2k+mg.
__global__ __launch_bounds__(256) void centroid_k(const float* __restrict__ x,
                                                  u16* __restrict__ ch) {
  const int bn = blockIdx.x;          // b*Nn + n
  const int tid = threadIdx.x;
  const int f4 = tid & 127;
  const int mg = tid >> 7;
  const int wv = tid >> 6, ln = tid & 63;
  const float4* xp = (const float4*)(x + (size_t)bn * (Mn * Dn));

  float4 a = {0.f, 0.f, 0.f, 0.f};
#pragma unroll
  for (int k = 0; k < 5; ++k) {
    const float4 v = xp[(2 * k + mg) * 128 + f4];
    a.x += v.x; a.y += v.y; a.z += v.z; a.w += v.w;
  }
  __shared__ float4 cred[128];
  if (mg == 1) cred[f4] = a;
  __syncthreads();

  float4 c = {0.f, 0.f, 0.f, 0.f};
  float cs = 0.f;
  if (mg == 0) {
    c = cred[f4];
    c.x += a.x; c.y += a.y; c.z += a.z; c.w += a.w;
    cs = c.x * c.x + c.y * c.y + c.z * c.z + c.w * c.w;
  }
#pragma unroll
  for (int t = 1; t < 64; t <<= 1) cs += __shfl_xor(cs, t, 64);
  __shared__ float csred[2];
  if (mg == 0 && ln == 0) csred[wv] = cs;
  __syncthreads();
  if (mg == 0) {
    const float scale = 1.0f / fmaxf(sqrtf(csred[0] + csred[1]), EPSV);
    const u16 h0 = f2bf(c.x * scale), h1 = f2bf(c.y * scale);
    const u16 h2 = f2bf(c.z * scale), h3 = f2bf(c.w * scale);
    uint2 w;
    w.x = (u32)h0 | ((u32)h1 << 16);
    w.y = (u32)h2 | ((u32)h3 << 16);
    ((uint2*)(ch + (size_t)bn * Dn))[f4] = w;
  }
}

// Kernel 2: 16 rows x 64 centroids per block; 4 waves split K (128 each).
// Row sq-norms computed in-flight from the A-tile this block already reads.
__global__ __launch_bounds__(256) void gemm_loss_k(const float* __restrict__ x,
                                                   const u16* __restrict__ ch,
                                                   const float* __restrict__ wp,
                                                   const float* __restrict__ bp,
                                                   float* __restrict__ partial) {
  const int b = blockIdx.x / (NMn / RT);
  const int rt = blockIdx.x % (NMn / RT);
  const int row0 = rt * RT;
  const int tid = threadIdx.x, wv = tid >> 6, ln = tid & 63;
  const int lr = ln & 15;          // A-row / B-col fragment index
  const int lkb = (ln >> 4) * 8;   // k offset within 32-wide K-step
  const int k0 = wv * 128;         // this wave's K-quarter

  const float* arow = x + ((size_t)b * NMn + row0 + lr) * Dn + k0 + lkb;
  const u16* brow = ch + ((size_t)b * Nn + lr) * Dn + k0 + lkb;

  f32x4 acc0 = {0.f, 0.f, 0.f, 0.f};
  f32x4 acc1 = acc0, acc2 = acc0, acc3 = acc0;
  float sq = 0.f;   // per-lane partial of row lr's squared norm

#pragma unroll
  for (int kk = 0; kk < 128; kk += 32) {
    const float4 f0 = *(const float4*)(arow + kk);
    const float4 f1 = *(const float4*)(arow + kk + 4);
    const bf16x8 b0 = *(const bf16x8*)(brow + kk);
    const bf16x8 b1 = *(const bf16x8*)(brow + 16 * Dn + kk);
    const bf16x8 b2 = *(const bf16x8*)(brow + 32 * Dn + kk);
    const bf16x8 b3 = *(const bf16x8*)(brow + 48 * Dn + kk);
    const float v[8] = {f0.x, f0.y, f0.z, f0.w, f1.x, f1.y, f1.z, f1.w};
    bf16x8 ah;
#pragma unroll
    for (int i = 0; i < 8; ++i) {
      ah[i] = (__bf16)v[i];           // native cast -> v_cvt_pk_bf16_f32 (RNE)
      sq = fmaf(v[i], v[i], sq);
    }
    acc0 = __builtin_amdgcn_mfma_f32_16x16x32_bf16(ah, b0, acc0, 0, 0, 0);
    acc1 = __builtin_amdgcn_mfma_f32_16x16x32_bf16(ah, b1, acc1, 0, 0, 0);
    acc2 = __builtin_amdgcn_mfma_f32_16x16x32_bf16(ah, b2, acc2, 0, 0, 0);
    acc3 = __builtin_amdgcn_mfma_f32_16x16x32_bf16(ah, b3, acc3, 0, 0, 0);
  }

  // reduce sq across the 4 lane-groups (lanes with equal lr)
  sq += __shfl_xor(sq, 16, 64);
  sq += __shfl_xor(sq, 32, 64);
  __shared__ float SQ[4][RT];      // per-wave K-quarter row norms
  if (ln < RT) SQ[wv][lr] = sq;

  // C/D layout: col = lane&15, row = (lane>>4)*4 + reg  (verified rounds 2-4)
  __shared__ float S[4][RT][65];   // per-wave partial sums
  const int orow = (ln >> 4) * 4;
#pragma unroll
  for (int r = 0; r < 4; ++r) {
    S[wv][orow + r][lr] = acc0[r];
    S[wv][orow + r][16 + lr] = acc1[r];
    S[wv][orow + r][32 + lr] = acc2[r];
    S[wv][orow + r][48 + lr] = acc3[r];
  }
  __syncthreads();

  // CE: wave wv handles rows wv*4 .. wv*4+3; lanes = 64 speaker columns
  const float W = *wp, Bb = *bp;
  float acc_nll = 0.f;
#pragma unroll
  for (int i = 0; i < 4; ++i) {
    const int r = wv * 4 + i;
    const int krow = row0 + r;
    const int spk = krow / Mn;
    const float rn = S[0][r][ln] + S[1][r][ln] + S[2][r][ln] + S[3][r][ln];
    const float x2 = SQ[0][r] + SQ[1][r] + SQ[2][r] + SQ[3][r];
    const float xn = sqrtf(x2);
    const float inv_xn = 1.0f / fmaxf(xn, EPSV);
    const float rspk = __shfl(rn, spk, 64);
    float sv = rn * inv_xn;
    if (ln == spk) {
      const float num = (float)Mn * rspk - x2;
      const float en = sqrtf(fmaxf((float)(Mn * Mn) - 2.0f * (float)Mn * rspk + x2, 0.f));
      sv = num / fmaxf(xn * en, EPSV);
    }
    const float logit = W * sv + Bb;
    const float lspk = __shfl(logit, spk, 64);
    float mx = logit;
#pragma unroll
    for (int t = 1; t < 64; t <<= 1) mx = fmaxf(mx, __shfl_xor(mx, t, 64));
    float se = expf(logit - mx);
#pragma unroll
    for (int t = 1; t < 64; t <<= 1) se += __shfl_xor(se, t, 64);
    acc_nll += (mx + logf(se)) - lspk;   // wave-uniform
  }
  __shared__ float nred[4];
  if (ln == 0) nred[wv] = acc_nll;
  __syncthreads();
  if (tid == 0) partial[blockIdx.x] = nred[0] + nred[1] + nred[2] + nred[3];
}

// Kernel 3: deterministic final reduction of 2560 per-block partials.
__global__ __launch_bounds__(256) void reduce_k(const float* __restrict__ partial,
                                                float* __restrict__ out) {
  const int tid = threadIdx.x;
  float s = 0.f;
  for (int i = tid; i < NBLK2; i += 256) s += partial[i];
#pragma unroll
  for (int t = 1; t < 64; t <<= 1) s += __shfl_xor(s, t, 64);
  __shared__ float red[4];
  if ((tid & 63) == 0) red[tid >> 6] = s;
  __syncthreads();
  if (tid == 0) out[0] = (red[0] + red[1] + red[2] + red[3]) * (1.0f / (float)(Bn * NMn));
}

// ---------------- fallback path (round-1 structure, known-good) ----------------
static constexpr int ROWS = 8;
static constexpr int DCHUNK = 128;
static constexpr int CPAD = DCHUNK + 1;

__global__ __launch_bounds__(256) void centroid_fb_k(const float* __restrict__ x,
                                                     float* __restrict__ c) {
  const int bn = blockIdx.x;
  const float* xp = x + (size_t)bn * Mn * Dn;
  const int tid = threadIdx.x;
  float a0 = 0.f, a1 = 0.f;
#pragma unroll
  for (int m = 0; m < Mn; ++m) {
    a0 += xp[m * Dn + tid];
    a1 += xp[m * Dn + tid + 256];
  }
  float s = a0 * a0 + a1 * a1;
#pragma unroll
  for (int m = 1; m < 64; m <<= 1) s += __shfl_xor(s, m, 64);
  __shared__ float red[4];
  const int wv = tid >> 6, ln = tid & 63;
  if (ln == 0) red[wv] = s;
  __syncthreads();
  const float tot = red[0] + red[1] + red[2] + red[3];
  const float scale = 1.0f / fmaxf(sqrtf(tot), EPSV);
  float* cp = c + (size_t)bn * Dn;
  cp[tid] = a0 * scale;
  cp[tid + 256] = a1 * scale;
}

__global__ __launch_bounds__(256) void loss_fb_k(const float* __restrict__ x,
                                                 const float* __restrict__ c,
                                                 const float* __restrict__ wp,
                                                 const float* __restrict__ bp,
                                                 float* __restrict__ out) {
  __shared__ __align__(16) float x_lds[ROWS * Dn];
  __shared__ float c_lds[Nn * CPAD];
  __shared__ float xn2s[ROWS];
  __shared__ float sim_lds[ROWS][Nn];

  const int tid = threadIdx.x;
  const int b = blockIdx.x / (NMn / ROWS);
  const int rblk = blockIdx.x % (NMn / ROWS);
  const int row0 = rblk * ROWS;
  const float* xrow = x + ((size_t)b * NMn + row0) * Dn;
  {
    const float4* xs = (const float4*)xrow;
    float4* xd = (float4*)x_lds;
#pragma unroll
    for (int i = tid; i < ROWS * Dn / 4; i += 256) xd[i] = xs[i];
  }
  __syncthreads();
  const int wv = tid >> 6, ln = tid & 63;
  for (int r = wv; r < ROWS; r += 4) {
    float s = 0.f;
#pragma unroll
    for (int j = ln; j < Dn; j += 64) {
      const float v = x_lds[r * Dn + j];
      s += v * v;
    }
#pragma unroll
    for (int m = 1; m < 64; m <<= 1) s += __shfl_xor(s, m, 64);
    if (ln == 0) xn2s[r] = s;
  }
  const int n = tid & 63;
  const int rg = tid >> 6;
  const int r0 = rg * 2, r1 = rg * 2 + 1;
  float s0 = 0.f, s1 = 0.f;
  const float* cb_base = c + (size_t)b * Nn * Dn;
  for (int cb = 0; cb < Dn; cb += DCHUNK) {
    __syncthreads();
    for (int i = tid; i < Nn * DCHUNK; i += 256) {
      const int nn = i / DCHUNK;
      const int j = i & (DCHUNK - 1);
      c_lds[nn * CPAD + j] = cb_base[(size_t)nn * Dn + cb + j];
    }
    __syncthreads();
#pragma unroll 16
    for (int j = 0; j < DCHUNK; ++j) {
      const float cv = c_lds[n * CPAD + j];
      s0 = fmaf(x_lds[r0 * Dn + cb + j], cv, s0);
      s1 = fmaf(x_lds[r1 * Dn + cb + j], cv, s1);
    }
  }
  sim_lds[r0][n] = s0;
  sim_lds[r1][n] = s1;
  __syncthreads();
  const float W = *wp, Bb = *bp;
  float acc_nll = 0.f;
  for (int r = wv; r < ROWS; r += 4) {
    const int k = row0 + r;
    const int spk = k / Mn;
    const float rn = sim_lds[r][ln];
    const float x2 = xn2s[r];
    const float xn = sqrtf(x2);
    const float inv_xn = 1.0f / fmaxf(xn, EPSV);
    const float rspk = sim_lds[r][spk];
    float sv = rn * inv_xn;
    if (ln == spk) {
      const float num = (float)Mn * rspk - x2;
      const float en = sqrtf(fmaxf((float)(Mn * Mn) - 2.0f * (float)Mn * rspk + x2, 0.f));
      sv = num / fmaxf(xn * en, EPSV);
    }
    const float logit = W * sv + Bb;
    const float lspk = __shfl(logit, spk, 64);
    float mx = logit;
#pragma unroll
    for (int m = 1; m < 64; m <<= 1) mx = fmaxf(mx, __shfl_xor(mx, m, 64));
    float se = expf(logit - mx);
#pragma unroll
    for (int m = 1; m < 64; m <<= 1) se += __shfl_xor(se, m, 64);
    acc_nll += (mx + logf(se)) - lspk;
  }
  __shared__ float nred[4];
  if (ln == 0) nred[wv] = acc_nll;
  __syncthreads();
  if (tid == 0)
    atomicAdd(out, (nred[0] + nred[1] + nred[2] + nred[3]) * (1.0f / (float)(Bn * NMn)));
}

extern "C" void kernel_launch(void* const* d_in, const int* in_sizes, int n_in,
                              void* d_out, int out_size, void* d_ws, size_t ws_size,
                              hipStream_t stream) {
  const float* x = (const float*)d_in[0];
  const float* w = (const float*)d_in[1];
  const float* b = (const float*)d_in[2];
  float* out = (float*)d_out;

  const size_t CSZ = (size_t)Bn * Nn * Dn * sizeof(u16);    // 4,194,304
  const size_t PSZ = (size_t)NBLK2 * sizeof(float);         //    10,240
  const size_t NEED = CSZ + PSZ;                            //  ~4.2 MB

  if (ws_size >= NEED) {
    char* p = (char*)d_ws;
    u16* ch = (u16*)p;      p += CSZ;
    float* partial = (float*)p;
    hipLaunchKernelGGL(centroid_k, dim3(Bn * Nn), dim3(256), 0, stream, x, ch);
    hipLaunchKernelGGL(gemm_loss_k, dim3(NBLK2), dim3(256), 0, stream,
                       x, ch, w, b, partial);
    hipLaunchKernelGGL(reduce_k, dim3(1), dim3(256), 0, stream, partial, out);
  } else {
    float* c = (float*)d_ws;  // 8 MB
    hipMemsetAsync(out, 0, sizeof(float), stream);
    hipLaunchKernelGGL(centroid_fb_k, dim3(Bn * Nn), dim3(256), 0, stream, x, c);
    hipLaunchKernelGGL(loss_fb_k, dim3(Bn * (NMn / ROWS)), dim3(256), 0, stream,
                       x, c, w, b, out);
  }
}

// Round 6
// 46.333 us; speedup vs baseline: 12.8319x; 1.1575x over previous
//
#include <hip/hip_runtime.h>
#include <math.h>

static constexpr int Bn = 64;
static constexpr int Nn = 64;
static constexpr int Mn = 10;
static constexpr int Dn = 512;
static constexpr int NMn = Nn * Mn;      // 640
static constexpr int RT = 16;            // rows per block (kernel 2)
static constexpr int NBLK2 = Bn * (NMn / RT);  // 2560
static constexpr float EPSV = 1e-12f;

typedef unsigned short u16;
typedef unsigned int u32;
typedef __attribute__((ext_vector_type(8))) __bf16 bf16x8;
typedef __attribute__((ext_vector_type(4))) float f32x4;

static __device__ __forceinline__ u16 f2bf(float f) {
  u32 u = __float_as_uint(f);
  u = u + 0x7fffu + ((u >> 16) & 1u);   // round-to-nearest-even
  return (u16)(u >> 16);
}

// ---------------- fast path ----------------
// ch2 layout: [b][kblk=k/32][n][koff=k%32] bf16  (fragment-tiled so k2's
// B loads are 1KB fully-coalesced per wave instruction: 16 consecutive
// 64B lines, each filled by 4 lane-groups)

// Kernel 1: per (b,n): normalized centroid -> bf16, tiled layout.
// Thread t: float4-column f4=t&127, parity mg=t>>7 covers m = 2k+mg.
__global__ __launch_bounds__(256) void centroid_k(const float* __restrict__ x,
                                                  u16* __restrict__ ch2) {
  const int bn = blockIdx.x;          // b*Nn + n
  const int tid = threadIdx.x;
  const int f4 = tid & 127;
  const int mg = tid >> 7;
  const int wv = tid >> 6, ln = tid & 63;
  const float4* xp = (const float4*)(x + (size_t)bn * (Mn * Dn));

  float4 a = {0.f, 0.f, 0.f, 0.f};
#pragma unroll
  for (int k = 0; k < 5; ++k) {
    const float4 v = xp[(2 * k + mg) * 128 + f4];
    a.x += v.x; a.y += v.y; a.z += v.z; a.w += v.w;
  }
  __shared__ float4 cred[128];
  if (mg == 1) cred[f4] = a;
  __syncthreads();

  float4 c = {0.f, 0.f, 0.f, 0.f};
  float cs = 0.f;
  if (mg == 0) {
    c = cred[f4];
    c.x += a.x; c.y += a.y; c.z += a.z; c.w += a.w;
    cs = c.x * c.x + c.y * c.y + c.z * c.z + c.w * c.w;
  }
#pragma unroll
  for (int t = 1; t < 64; t <<= 1) cs += __shfl_xor(cs, t, 64);
  __shared__ float csred[2];
  if (mg == 0 && ln == 0) csred[wv] = cs;
  __syncthreads();
  if (mg == 0) {
    const float scale = 1.0f / fmaxf(sqrtf(csred[0] + csred[1]), EPSV);
    const u16 h0 = f2bf(c.x * scale), h1 = f2bf(c.y * scale);
    const u16 h2 = f2bf(c.z * scale), h3 = f2bf(c.w * scale);
    uint2 w;
    w.x = (u32)h0 | ((u32)h1 << 16);
    w.y = (u32)h2 | ((u32)h3 << 16);
    // k = 4*f4 .. 4*f4+3  ->  kblk = f4>>3, koff = (f4&7)*4  (never crosses 32)
    const int n = bn & (Nn - 1), bb = bn >> 6;
    const size_t off = (((size_t)bb * 16 + (f4 >> 3)) * Nn + n) * 32 + ((f4 & 7) * 4);
    *(uint2*)(ch2 + off) = w;
  }
}

// Kernel 2: 16 rows x 64 centroids per block; 4 waves split K (128 each).
// B loads from tiled ch2 (coalesced); A direct fp32 with in-flight sq-norms.
__global__ __launch_bounds__(256) void gemm_loss_k(const float* __restrict__ x,
                                                   const u16* __restrict__ ch2,
                                                   const float* __restrict__ wp,
                                                   const float* __restrict__ bp,
                                                   float* __restrict__ partial) {
  const int b = blockIdx.x / (NMn / RT);
  const int rt = blockIdx.x % (NMn / RT);
  const int row0 = rt * RT;
  const int tid = threadIdx.x, wv = tid >> 6, ln = tid & 63;
  const int lr = ln & 15;          // A-row / B-col fragment index
  const int lkb = (ln >> 4) * 8;   // k offset within 32-wide K-step
  const int k0 = wv * 128;         // this wave's K-quarter

  const float* arow = x + ((size_t)b * NMn + row0 + lr) * Dn + k0 + lkb;
  // ch2[b][kblk][n][koff]: this wave starts at kblk = wv*4
  const u16* brow = ch2 + (((size_t)b * 16 + wv * 4) * Nn) * 32 + (size_t)lr * 32 + lkb;

  f32x4 acc0 = {0.f, 0.f, 0.f, 0.f};
  f32x4 acc1 = acc0, acc2 = acc0, acc3 = acc0;
  float sq = 0.f;   // per-lane partial of row lr's squared norm

#pragma unroll
  for (int kk = 0; kk < 128; kk += 32) {
    const int kb = kk >> 5;                       // kblk within quarter
    const u16* bp8 = brow + (size_t)kb * (Nn * 32);
    const float4 f0 = *(const float4*)(arow + kk);
    const float4 f1 = *(const float4*)(arow + kk + 4);
    const bf16x8 b0 = *(const bf16x8*)(bp8);
    const bf16x8 b1 = *(const bf16x8*)(bp8 + 16 * 32);
    const bf16x8 b2 = *(const bf16x8*)(bp8 + 32 * 32);
    const bf16x8 b3 = *(const bf16x8*)(bp8 + 48 * 32);
    const float v[8] = {f0.x, f0.y, f0.z, f0.w, f1.x, f1.y, f1.z, f1.w};
    bf16x8 ah;
#pragma unroll
    for (int i = 0; i < 8; ++i) {
      ah[i] = (__bf16)v[i];           // native cast (RNE)
      sq = fmaf(v[i], v[i], sq);
    }
    acc0 = __builtin_amdgcn_mfma_f32_16x16x32_bf16(ah, b0, acc0, 0, 0, 0);
    acc1 = __builtin_amdgcn_mfma_f32_16x16x32_bf16(ah, b1, acc1, 0, 0, 0);
    acc2 = __builtin_amdgcn_mfma_f32_16x16x32_bf16(ah, b2, acc2, 0, 0, 0);
    acc3 = __builtin_amdgcn_mfma_f32_16x16x32_bf16(ah, b3, acc3, 0, 0, 0);
  }

  // reduce sq across the 4 lane-groups (lanes with equal lr)
  sq += __shfl_xor(sq, 16, 64);
  sq += __shfl_xor(sq, 32, 64);
  __shared__ float SQ[4][RT];      // per-wave K-quarter row norms
  if (ln < RT) SQ[wv][lr] = sq;

  // C/D layout: col = lane&15, row = (lane>>4)*4 + reg  (verified rounds 2-5)
  __shared__ float S[4][RT][65];   // per-wave partial sums
  const int orow = (ln >> 4) * 4;
#pragma unroll
  for (int r = 0; r < 4; ++r) {
    S[wv][orow + r][lr] = acc0[r];
    S[wv][orow + r][16 + lr] = acc1[r];
    S[wv][orow + r][32 + lr] = acc2[r];
    S[wv][orow + r][48 + lr] = acc3[r];
  }
  __syncthreads();

  // CE: wave wv handles rows wv*4 .. wv*4+3; lanes = 64 speaker columns
  const float W = *wp, Bb = *bp;
  float acc_nll = 0.f;
#pragma unroll
  for (int i = 0; i < 4; ++i) {
    const int r = wv * 4 + i;
    const int krow = row0 + r;
    const int spk = krow / Mn;
    const float rn = S[0][r][ln] + S[1][r][ln] + S[2][r][ln] + S[3][r][ln];
    const float x2 = SQ[0][r] + SQ[1][r] + SQ[2][r] + SQ[3][r];
    const float xn = sqrtf(x2);
    const float inv_xn = 1.0f / fmaxf(xn, EPSV);
    const float rspk = __shfl(rn, spk, 64);
    float sv = rn * inv_xn;
    if (ln == spk) {
      const float num = (float)Mn * rspk - x2;
      const float en = sqrtf(fmaxf((float)(Mn * Mn) - 2.0f * (float)Mn * rspk + x2, 0.f));
      sv = num / fmaxf(xn * en, EPSV);
    }
    const float logit = W * sv + Bb;
    const float lspk = __shfl(logit, spk, 64);
    float mx = logit;
#pragma unroll
    for (int t = 1; t < 64; t <<= 1) mx = fmaxf(mx, __shfl_xor(mx, t, 64));
    float se = expf(logit - mx);
#pragma unroll
    for (int t = 1; t < 64; t <<= 1) se += __shfl_xor(se, t, 64);
    acc_nll += (mx + logf(se)) - lspk;   // wave-uniform
  }
  __shared__ float nred[4];
  if (ln == 0) nred[wv] = acc_nll;
  __syncthreads();
  if (tid == 0) partial[blockIdx.x] = nred[0] + nred[1] + nred[2] + nred[3];
}

// Kernel 3: deterministic final reduction of 2560 per-block partials.
__global__ __launch_bounds__(256) void reduce_k(const float* __restrict__ partial,
                                                float* __restrict__ out) {
  const int tid = threadIdx.x;
  float s = 0.f;
  for (int i = tid; i < NBLK2; i += 256) s += partial[i];
#pragma unroll
  for (int t = 1; t < 64; t <<= 1) s += __shfl_xor(s, t, 64);
  __shared__ float red[4];
  if ((tid & 63) == 0) red[tid >> 6] = s;
  __syncthreads();
  if (tid == 0) out[0] = (red[0] + red[1] + red[2] + red[3]) * (1.0f / (float)(Bn * NMn));
}

// ---------------- fallback path (round-1 structure, known-good) ----------------
static constexpr int ROWS = 8;
static constexpr int DCHUNK = 128;
static constexpr int CPAD = DCHUNK + 1;

__global__ __launch_bounds__(256) void centroid_fb_k(const float* __restrict__ x,
                                                     float* __restrict__ c) {
  const int bn = blockIdx.x;
  const float* xp = x + (size_t)bn * Mn * Dn;
  const int tid = threadIdx.x;
  float a0 = 0.f, a1 = 0.f;
#pragma unroll
  for (int m = 0; m < Mn; ++m) {
    a0 += xp[m * Dn + tid];
    a1 += xp[m * Dn + tid + 256];
  }
  float s = a0 * a0 + a1 * a1;
#pragma unroll
  for (int m = 1; m < 64; m <<= 1) s += __shfl_xor(s, m, 64);
  __shared__ float red[4];
  const int wv = tid >> 6, ln = tid & 63;
  if (ln == 0) red[wv] = s;
  __syncthreads();
  const float tot = red[0] + red[1] + red[2] + red[3];
  const float scale = 1.0f / fmaxf(sqrtf(tot), EPSV);
  float* cp = c + (size_t)bn * Dn;
  cp[tid] = a0 * scale;
  cp[tid + 256] = a1 * scale;
}

__global__ __launch_bounds__(256) void loss_fb_k(const float* __restrict__ x,
                                                 const float* __restrict__ c,
                                                 const float* __restrict__ wp,
                                                 const float* __restrict__ bp,
                                                 float* __restrict__ out) {
  __shared__ __align__(16) float x_lds[ROWS * Dn];
  __shared__ float c_lds[Nn * CPAD];
  __shared__ float xn2s[ROWS];
  __shared__ float sim_lds[ROWS][Nn];

  const int tid = threadIdx.x;
  const int b = blockIdx.x / (NMn / ROWS);
  const int rblk = blockIdx.x % (NMn / ROWS);
  const int row0 = rblk * ROWS;
  const float* xrow = x + ((size_t)b * NMn + row0) * Dn;
  {
    const float4* xs = (const float4*)xrow;
    float4* xd = (float4*)x_lds;
#pragma unroll
    for (int i = tid; i < ROWS * Dn / 4; i += 256) xd[i] = xs[i];
  }
  __syncthreads();
  const int wv = tid >> 6, ln = tid & 63;
  for (int r = wv; r < ROWS; r += 4) {
    float s = 0.f;
#pragma unroll
    for (int j = ln; j < Dn; j += 64) {
      const float v = x_lds[r * Dn + j];
      s += v * v;
    }
#pragma unroll
    for (int m = 1; m < 64; m <<= 1) s += __shfl_xor(s, m, 64);
    if (ln == 0) xn2s[r] = s;
  }
  const int n = tid & 63;
  const int rg = tid >> 6;
  const int r0 = rg * 2, r1 = rg * 2 + 1;
  float s0 = 0.f, s1 = 0.f;
  const float* cb_base = c + (size_t)b * Nn * Dn;
  for (int cb = 0; cb < Dn; cb += DCHUNK) {
    __syncthreads();
    for (int i = tid; i < Nn * DCHUNK; i += 256) {
      const int nn = i / DCHUNK;
      const int j = i & (DCHUNK - 1);
      c_lds[nn * CPAD + j] = cb_base[(size_t)nn * Dn + cb + j];
    }
    __syncthreads();
#pragma unroll 16
    for (int j = 0; j < DCHUNK; ++j) {
      const float cv = c_lds[n * CPAD + j];
      s0 = fmaf(x_lds[r0 * Dn + cb + j], cv, s0);
      s1 = fmaf(x_lds[r1 * Dn + cb + j], cv, s1);
    }
  }
  sim_lds[r0][n] = s0;
  sim_lds[r1][n] = s1;
  __syncthreads();
  const float W = *wp, Bb = *bp;
  float acc_nll = 0.f;
  for (int r = wv; r < ROWS; r += 4) {
    const int k = row0 + r;
    const int spk = k / Mn;
    const float rn = sim_lds[r][ln];
    const float x2 = xn2s[r];
    const float xn = sqrtf(x2);
    const float inv_xn = 1.0f / fmaxf(xn, EPSV);
    const float rspk = sim_lds[r][spk];
    float sv = rn * inv_xn;
    if (ln == spk) {
      const float num = (float)Mn * rspk - x2;
      const float en = sqrtf(fmaxf((float)(Mn * Mn) - 2.0f * (float)Mn * rspk + x2, 0.f));
      sv = num / fmaxf(xn * en, EPSV);
    }
    const float logit = W * sv + Bb;
    const float lspk = __shfl(logit, spk, 64);
    float mx = logit;
#pragma unroll
    for (int m = 1; m < 64; m <<= 1) mx = fmaxf(mx, __shfl_xor(mx, m, 64));
    float se = expf(logit - mx);
#pragma unroll
    for (int m = 1; m < 64; m <<= 1) se += __shfl_xor(se, m, 64);
    acc_nll += (mx + logf(se)) - lspk;
  }
  __shared__ float nred[4];
  if (ln == 0) nred[wv] = acc_nll;
  __syncthreads();
  if (tid == 0)
    atomicAdd(out, (nred[0] + nred[1] + nred[2] + nred[3]) * (1.0f / (float)(Bn * NMn)));
}

extern "C" void kernel_launch(void* const* d_in, const int* in_sizes, int n_in,
                              void* d_out, int out_size, void* d_ws, size_t ws_size,
                              hipStream_t stream) {
  const float* x = (const float*)d_in[0];
  const float* w = (const float*)d_in[1];
  const float* b = (const float*)d_in[2];
  float* out = (float*)d_out;

  const size_t CSZ = (size_t)Bn * Nn * Dn * sizeof(u16);    // 4,194,304
  const size_t PSZ = (size_t)NBLK2 * sizeof(float);         //    10,240
  const size_t NEED = CSZ + PSZ;                            //  ~4.2 MB

  if (ws_size >= NEED) {
    char* p = (char*)d_ws;
    u16* ch2 = (u16*)p;     p += CSZ;
    float* partial = (float*)p;
    hipLaunchKernelGGL(centroid_k, dim3(Bn * Nn), dim3(256), 0, stream, x, ch2);
    hipLaunchKernelGGL(gemm_loss_k, dim3(NBLK2), dim3(256), 0, stream,
                       x, ch2, w, b, partial);
    hipLaunchKernelGGL(reduce_k, dim3(1), dim3(256), 0, stream, partial, out);
  } else {
    float* c = (float*)d_ws;  // 8 MB
    hipMemsetAsync(out, 0, sizeof(float), stream);
    hipLaunchKernelGGL(centroid_fb_k, dim3(Bn * Nn), dim3(256), 0, stream, x, c);
    hipLaunchKernelGGL(loss_fb_k, dim3(Bn * (NMn / ROWS)), dim3(256), 0, stream,
                       x, c, w, b, out);
  }
}